// Round 4
// baseline (262.537 us; speedup 1.0000x reference)
//
#include <hip/hip_runtime.h>
#include <hip/hip_bf16.h>

#define LN_EPS 1e-5f

typedef __attribute__((ext_vector_type(8))) short s8v;
typedef __attribute__((ext_vector_type(4))) float f32x4;

// ---------- helpers ----------
__device__ __forceinline__ float wred_sum(float v) {
#pragma unroll
  for (int o = 32; o > 0; o >>= 1) v += __shfl_xor(v, o, 64);
  return v;
}
__device__ __forceinline__ float wred_max(float v) {
#pragma unroll
  for (int o = 32; o > 0; o >>= 1) v = fmaxf(v, __shfl_xor(v, o, 64));
  return v;
}
__device__ __forceinline__ float bsum256(float v, float* s4) {
  v = wred_sum(v);
  int lane = threadIdx.x & 63, w = threadIdx.x >> 6;
  __syncthreads();
  if (lane == 0) s4[w] = v;
  __syncthreads();
  return s4[0] + s4[1] + s4[2] + s4[3];
}
__device__ __forceinline__ float bmax256(float v, float* s4) {
  v = wred_max(v);
  int lane = threadIdx.x & 63, w = threadIdx.x >> 6;
  __syncthreads();
  if (lane == 0) s4[w] = v;
  __syncthreads();
  return fmaxf(fmaxf(s4[0], s4[1]), fmaxf(s4[2], s4[3]));
}
__device__ __forceinline__ float bf2f(unsigned short u) {
  union { unsigned int i; float f; } c;
  c.i = ((unsigned int)u) << 16;
  return c.f;
}
__device__ __forceinline__ unsigned short f2bf(float f) {
  __hip_bfloat16 h = (__hip_bfloat16)f;
  return *(unsigned short*)&h;
}
__device__ __forceinline__ void async_cp16(const __hip_bfloat16* g, __hip_bfloat16* l) {
  __builtin_amdgcn_global_load_lds(
      (const __attribute__((address_space(1))) unsigned int*)g,
      (__attribute__((address_space(3))) unsigned int*)l, 16, 0, 0);
}

// ---------- fused prep: ln(wpe), ln(wte[tokens])->bf16, W1^T, W2^T, zero ctx ----------
__global__ void prep_k(const float* __restrict__ wpe, const float* __restrict__ wte,
                       const int* __restrict__ tokens,
                       const float* __restrict__ g_p, const float* __restrict__ g_e,
                       const float* __restrict__ ff_w1, const float* __restrict__ ff_w2,
                       float* __restrict__ p0, unsigned short* __restrict__ p0b,
                       unsigned short* __restrict__ e,
                       unsigned short* __restrict__ w1T, unsigned short* __restrict__ w2T,
                       float* __restrict__ ctx) {
  __shared__ float lds[64][65];
  int bx = blockIdx.x, t = threadIdx.x;
  int w = t >> 6, lane = t & 63;

  if (bx < 5120) {  // layernorm roles, wave per row
    int row, tok;
    const float* g;
    const float4* src;
    if (bx < 1024) {           // p = LN(wpe[:4096], g_p)
      row = bx * 4 + w;
      src = (const float4*)(wpe + (size_t)row * 256);
      g = g_p;
    } else {                   // e = LN(wte[tokens], g_e)
      row = (bx - 1024) * 4 + w;
      tok = tokens[row];
      src = (const float4*)(wte + (size_t)tok * 256);
      g = g_e;
    }
    float4 v = src[lane];
    float mean = wred_sum(v.x + v.y + v.z + v.w) * (1.f / 256.f);
    float4 d = {v.x - mean, v.y - mean, v.z - mean, v.w - mean};
    float var = wred_sum(d.x * d.x + d.y * d.y + d.z * d.z + d.w * d.w) * (1.f / 256.f);
    float r = rsqrtf(var + LN_EPS);
    float4 gv = ((const float4*)g)[lane];
    float4 o = {d.x * r * gv.x, d.y * r * gv.y, d.z * r * gv.z, d.w * r * gv.w};
    ushort4 ob = {f2bf(o.x), f2bf(o.y), f2bf(o.z), f2bf(o.w)};
    if (bx < 1024) {
      ((float4*)(p0 + (size_t)row * 256))[lane] = o;
      ((ushort4*)(p0b + (size_t)row * 256))[lane] = ob;
    } else {
      ((ushort4*)(e + (size_t)row * 256))[lane] = ob;
    }
    return;
  }
  if (bx < 5248) {  // transpose-cast: W1 (256x1024) or W2 (1024x256)
    const float* in; unsigned short* out; int M, N, bxx, byy;
    if (bx < 5184) { int i = bx - 5120; in = ff_w1; out = w1T; M = 256; N = 1024; bxx = i & 3; byy = i >> 2; }
    else           { int i = bx - 5184; in = ff_w2; out = w2T; M = 1024; N = 256; bxx = i & 15; byy = i >> 4; }
    int x = t & 63, y4 = t >> 6;
    int r0 = bxx * 64, c0 = byy * 64;
#pragma unroll
    for (int i = 0; i < 16; ++i) {
      int r = y4 * 16 + i;
      lds[r][x] = in[(size_t)(r0 + r) * N + c0 + x];
    }
    __syncthreads();
#pragma unroll
    for (int i = 0; i < 16; ++i) {
      int a = y4 * 16 + i;
      out[(size_t)(c0 + a) * M + r0 + x] = f2bf(lds[x][a]);
    }
    return;
  }
  // bx == 5248: zero ctx
  for (int i = t; i < 6 * 4 * 256; i += 256) ctx[i] = 0.f;
}

// ---------- MFMA GEMM: C(MxN) = A(MxK) @ B, B given as BT(NxK) ----------
// Tile BMx64, BK=64, 2x2 waves, async global->LDS, XOR-swizzled chunks.
// mode 0: none; 1: exact gelu; 2: += res(f32 MxN).
template <int TM>
__global__ __launch_bounds__(256) void mfma_gemm(
    const __hip_bfloat16* __restrict__ A, const __hip_bfloat16* __restrict__ BT,
    __hip_bfloat16* __restrict__ Cout, const float* __restrict__ res,
    int M, int N, int K, int mode) {
  constexpr int BM = TM * 32;
  __shared__ __hip_bfloat16 As[BM * 64];
  __shared__ __hip_bfloat16 Bs[64 * 64];
  const int t = threadIdx.x;
  const int lane = t & 63, wave = t >> 6;
  const int wr = wave >> 1, wc = wave & 1;
  const int fr = lane & 15, quad = lane >> 4;
  const int m0 = blockIdx.x * BM, n0 = blockIdx.y * 64;

  f32x4 acc[TM][2];
#pragma unroll
  for (int i = 0; i < TM; ++i)
#pragma unroll
    for (int j = 0; j < 2; ++j) acc[i][j] = (f32x4){0.f, 0.f, 0.f, 0.f};

  for (int k0 = 0; k0 < K; k0 += 64) {
    __syncthreads();
#pragma unroll
    for (int j = 0; j < TM; ++j) {
      int ld = wave * TM + j;
      int slot = ld * 64 + lane;
      int m = slot >> 3, c = slot & 7;
      const __hip_bfloat16* g = A + (size_t)(m0 + m) * K + k0 + ((c ^ (m & 7)) << 3);
      async_cp16(g, As + ld * 512);
    }
#pragma unroll
    for (int j = 0; j < 2; ++j) {
      int ld = wave * 2 + j;
      int slot = ld * 64 + lane;
      int n = slot >> 3, c = slot & 7;
      const __hip_bfloat16* g = BT + (size_t)(n0 + n) * K + k0 + ((c ^ (n & 7)) << 3);
      async_cp16(g, Bs + ld * 512);
    }
    __syncthreads();
#pragma unroll
    for (int h = 0; h < 2; ++h) {
      s8v af[TM], bfv[2];
#pragma unroll
      for (int i = 0; i < TM; ++i) {
        int m = wr * TM * 16 + i * 16 + fr;
        int ch = (h * 4 + quad) ^ (m & 7);
        af[i] = *(const s8v*)(As + m * 64 + ch * 8);
      }
#pragma unroll
      for (int j = 0; j < 2; ++j) {
        int n = wc * 32 + j * 16 + fr;
        int ch = (h * 4 + quad) ^ (n & 7);
        bfv[j] = *(const s8v*)(Bs + n * 64 + ch * 8);
      }
#pragma unroll
      for (int i = 0; i < TM; ++i)
#pragma unroll
        for (int j = 0; j < 2; ++j)
          acc[i][j] = __builtin_amdgcn_mfma_f32_16x16x32_bf16(af[i], bfv[j], acc[i][j], 0, 0, 0);
    }
  }

#pragma unroll
  for (int i = 0; i < TM; ++i) {
#pragma unroll
    for (int j = 0; j < 2; ++j) {
#pragma unroll
      for (int r = 0; r < 4; ++r) {
        int row = m0 + wr * TM * 16 + i * 16 + quad * 4 + r;
        int col = n0 + wc * 32 + j * 16 + fr;
        float v = acc[i][j][r];
        if (mode == 1) v = 0.5f * v * (1.f + erff(v * 0.70710678118654752f));
        if (mode == 2) v += res[(size_t)row * N + col];
        Cout[(size_t)row * N + col] = (__hip_bfloat16)v;
      }
    }
  }
}

// ---------- qkv: q[l] = p_last @ Wq[l];  kv[l] = Wk[l] @ q[l] ----------
__global__ void qkv_k(const __hip_bfloat16* __restrict__ pB, const float* __restrict__ Wq,
                      const float* __restrict__ Wk, float* __restrict__ kv) {
  int l = blockIdx.x, t = threadIdx.x;
  __shared__ float qs[256];
  const __hip_bfloat16* plast = pB + (size_t)4095 * 256;
  const float* Wql = Wq + (size_t)l * 65536;
  float acc = 0.f;
#pragma unroll 8
  for (int d = 0; d < 256; ++d) acc += (float)plast[d] * Wql[d * 256 + t];
  qs[t] = acc;
  __syncthreads();
  const float* Wkl = Wk + (size_t)l * 65536;
  float kacc = 0.f;
#pragma unroll 8
  for (int e = 0; e < 256; ++e) kacc += Wkl[t * 256 + e] * qs[e];
  kv[l * 256 + t] = kacc;
}

// ---------- scores: s[l][t] = p[t] . kv[l] / 16 (wave per row, all 6 layers) ----------
__global__ void scores_k(const __hip_bfloat16* __restrict__ pB, const float* __restrict__ kv,
                         float* __restrict__ sc) {
  int w = threadIdx.x >> 6, lane = threadIdx.x & 63;
  int t = blockIdx.x * 4 + w;
  ushort4 pv = ((const ushort4*)((const unsigned short*)pB + (size_t)t * 256))[lane];
  float4 p = {bf2f(pv.x), bf2f(pv.y), bf2f(pv.z), bf2f(pv.w)};
#pragma unroll
  for (int l = 0; l < 6; ++l) {
    float4 kvv = ((const float4*)(kv + l * 256))[lane];
    float dot = p.x * kvv.x + p.y * kvv.y + p.z * kvv.z + p.w * kvv.w;
    dot = wred_sum(dot);
    if (lane == 0) sc[(size_t)l * 4096 + t] = dot * 0.0625f;
  }
}

// ---------- softmax (redundant per block) + ctx accumulation ----------
__global__ void ctx_sm_k(const unsigned short* __restrict__ e, const float* __restrict__ sc,
                         float* __restrict__ ctx) {
  int c = blockIdx.x, b = blockIdx.y, t = threadIdx.x;
  __shared__ float s4[4];
  __shared__ float wch[6][64];
  float wmax[6], winv[6];
#pragma unroll
  for (int l = 0; l < 6; ++l) {
    const float* scl = sc + (size_t)l * 4096;
    float lm = -1e30f;
    for (int i = t; i < 4096; i += 256) lm = fmaxf(lm, scl[i]);
    lm = bmax256(lm, s4);
    float ls = 0.f;
    for (int i = t; i < 4096; i += 256) ls += expf(scl[i] - lm);
    ls = bsum256(ls, s4);
    wmax[l] = lm; winv[l] = 1.f / ls;
  }
  for (int i = t; i < 6 * 64; i += 256) {
    int l = i >> 6, j = i & 63;
    wch[l][j] = expf(sc[(size_t)l * 4096 + c * 64 + j] - wmax[l]) * winv[l];
  }
  __syncthreads();
  const unsigned short* eb = e + ((size_t)b * 4096 + c * 64) * 256;
  float a[6] = {0.f, 0.f, 0.f, 0.f, 0.f, 0.f};
#pragma unroll 4
  for (int i = 0; i < 64; ++i) {
    float ev = bf2f(eb[(size_t)i * 256 + t]);
#pragma unroll
    for (int l = 0; l < 6; ++l) a[l] += wch[l][i] * ev;
  }
#pragma unroll
  for (int l = 0; l < 6; ++l) atomicAdd(&ctx[(l * 4 + b) * 256 + t], a[l]);
}

// ---------- proj through Wv (all layers) + residual + final LN ----------
__global__ void projfinal_k(const unsigned short* __restrict__ e, const float* __restrict__ p0,
                            const float* __restrict__ ctx, const float* __restrict__ Wv,
                            const float* __restrict__ gout, float* __restrict__ xln) {
  int b = blockIdx.x, t = threadIdx.x;
  float acc = bf2f(e[((size_t)(b * 4096 + 4095)) * 256 + t]) + p0[(size_t)4095 * 256 + t];
#pragma unroll
  for (int l = 0; l < 6; ++l) {
    const float* cl = ctx + (l * 4 + b) * 256;
    const float* W = Wv + (size_t)l * 65536;
#pragma unroll 8
    for (int d = 0; d < 256; ++d) acc += cl[d] * W[d * 256 + t];
  }
  __shared__ float s4[4];
  float mean = bsum256(acc, s4) * (1.f / 256.f);
  float d = acc - mean;
  float var = bsum256(d * d, s4) * (1.f / 256.f);
  xln[b * 256 + t] = d * rsqrtf(var + LN_EPS) * gout[t];
}

// ---------- logits ----------
__global__ void logits_k(const float* __restrict__ wte, const float* __restrict__ ge,
                         const float* __restrict__ xln, float* __restrict__ out) {
  int wv = threadIdx.x >> 6, lane = threadIdx.x & 63;
  int v = blockIdx.x * 4 + wv;
  float4 x = ((const float4*)(wte + (size_t)v * 256))[lane];
  float mean = wred_sum(x.x + x.y + x.z + x.w) * (1.f / 256.f);
  float4 d = {x.x - mean, x.y - mean, x.z - mean, x.w - mean};
  float var = wred_sum(d.x * d.x + d.y * d.y + d.z * d.z + d.w * d.w) * (1.f / 256.f);
  float r = rsqrtf(var + LN_EPS);
  float4 gv = ((const float4*)ge)[lane];
  float4 ln = {d.x * r * gv.x, d.y * r * gv.y, d.z * r * gv.z, d.w * r * gv.w};
#pragma unroll
  for (int b = 0; b < 4; ++b) {
    float4 xv = ((const float4*)(xln + b * 256))[lane];
    float dot = wred_sum(ln.x * xv.x + ln.y * xv.y + ln.z * xv.z + ln.w * xv.w);
    if (lane == 0) out[b * 32000 + v] = dot;
  }
}

// ---------- workspace layout (float units, 16B aligned) ----------
#define O_P0    ((size_t)0)         // f32 4096*256
#define O_E     ((size_t)1048576)   // bf16 16384*256 (2M fl)
#define O_P0B   ((size_t)3145728)   // bf16 4096*256 (512K fl)
#define O_W1T   ((size_t)3670016)   // bf16 1024*256
#define O_W2T   ((size_t)3801088)   // bf16 256*1024
#define O_HB    ((size_t)3932160)   // bf16 4096*1024 (2M fl)
#define O_PB    ((size_t)6029312)   // bf16 4096*256
#define O_KV    ((size_t)6553600)   // f32 6*256
#define O_SC    ((size_t)6555136)   // f32 6*4096
#define O_CTX   ((size_t)6579712)   // f32 6*4*256
#define O_XLN   ((size_t)6585856)   // f32 4*256

extern "C" void kernel_launch(void* const* d_in, const int* in_sizes, int n_in,
                              void* d_out, int out_size, void* d_ws, size_t ws_size,
                              hipStream_t stream) {
  const int*   tokens = (const int*)d_in[0];
  const float* wte    = (const float*)d_in[1];
  const float* wpe    = (const float*)d_in[2];
  const float* g_e    = (const float*)d_in[3];
  const float* g_p    = (const float*)d_in[4];
  const float* g_out  = (const float*)d_in[5];
  const float* ff_w1  = (const float*)d_in[6];
  const float* ff_w2  = (const float*)d_in[7];
  const float* Wq     = (const float*)d_in[8];
  const float* Wk     = (const float*)d_in[9];
  const float* Wv     = (const float*)d_in[10];
  float* out = (float*)d_out;
  float* ws = (float*)d_ws;

  float* p0 = ws + O_P0;
  unsigned short* e   = (unsigned short*)(ws + O_E);
  unsigned short* p0b = (unsigned short*)(ws + O_P0B);
  unsigned short* w1T = (unsigned short*)(ws + O_W1T);
  unsigned short* w2T = (unsigned short*)(ws + O_W2T);
  __hip_bfloat16* hB  = (__hip_bfloat16*)(ws + O_HB);
  __hip_bfloat16* pB  = (__hip_bfloat16*)(ws + O_PB);
  float* kv  = ws + O_KV;
  float* sc  = ws + O_SC;
  float* ctx = ws + O_CTX;
  float* xln = ws + O_XLN;

  // 1. fused prep (LNs, weight transposes, ctx zero)
  prep_k<<<5249, 256, 0, stream>>>(wpe, wte, tokens, g_p, g_e, ff_w1, ff_w2,
                                   p0, p0b, e, w1T, w2T, ctx);
  // 2. MLP1: h = gelu(p0 @ ff_w1)  [4096x1024x256]
  mfma_gemm<4><<<dim3(32, 16), 256, 0, stream>>>(
      (const __hip_bfloat16*)p0b, (const __hip_bfloat16*)w1T, hB, nullptr, 4096, 1024, 256, 1);
  // 3. MLP2: p = p0 + h @ ff_w2    [4096x256x1024]
  mfma_gemm<2><<<dim3(64, 4), 256, 0, stream>>>(
      hB, (const __hip_bfloat16*)w2T, pB, p0, 4096, 256, 1024, 2);
  // 4. q_last + kv = Wk @ q
  qkv_k<<<6, 256, 0, stream>>>(pB, Wq, Wk, kv);
  // 5. scores s[l][t] = p[t].kv[l]/16
  scores_k<<<1024, 256, 0, stream>>>(pB, kv, sc);
  // 6. softmax + ctx accumulation
  ctx_sm_k<<<dim3(64, 4), 256, 0, stream>>>(e, sc, ctx);
  // 7. Wv projection + residual + final LN
  projfinal_k<<<4, 256, 0, stream>>>(e, p0, ctx, Wv, g_out, xln);
  // 8. logits
  logits_k<<<8000, 256, 0, stream>>>(wte, g_e, xln, out);
}

// Round 5
// 165.732 us; speedup vs baseline: 1.5841x; 1.5841x over previous
//
#include <hip/hip_runtime.h>
#include <hip/hip_bf16.h>

#define LN_EPS 1e-5f

typedef __attribute__((ext_vector_type(8))) short s8v;
typedef __attribute__((ext_vector_type(4))) float f32x4;

// ---------- helpers ----------
__device__ __forceinline__ float wred_sum(float v) {
#pragma unroll
  for (int o = 32; o > 0; o >>= 1) v += __shfl_xor(v, o, 64);
  return v;
}
__device__ __forceinline__ float wred_max(float v) {
#pragma unroll
  for (int o = 32; o > 0; o >>= 1) v = fmaxf(v, __shfl_xor(v, o, 64));
  return v;
}
__device__ __forceinline__ float bsum256(float v, float* s4) {
  v = wred_sum(v);
  int lane = threadIdx.x & 63, w = threadIdx.x >> 6;
  __syncthreads();
  if (lane == 0) s4[w] = v;
  __syncthreads();
  return s4[0] + s4[1] + s4[2] + s4[3];
}
__device__ __forceinline__ float bf2f(unsigned short u) {
  union { unsigned int i; float f; } c;
  c.i = ((unsigned int)u) << 16;
  return c.f;
}
__device__ __forceinline__ unsigned short f2bf(float f) {
  __hip_bfloat16 h = (__hip_bfloat16)f;
  return *(unsigned short*)&h;
}
__device__ __forceinline__ void async_cp16(const __hip_bfloat16* g, __hip_bfloat16* l) {
  __builtin_amdgcn_global_load_lds(
      (const __attribute__((address_space(1))) unsigned int*)g,
      (__attribute__((address_space(3))) unsigned int*)l, 16, 0, 0);
}

// ---------- fused prep: ln(wpe), ln(wte[tokens])->bf16, W1^T, W2^T, zero accs ----------
__global__ void prep_k(const float* __restrict__ wpe, const float* __restrict__ wte,
                       const int* __restrict__ tokens,
                       const float* __restrict__ g_p, const float* __restrict__ g_e,
                       const float* __restrict__ ff_w1, const float* __restrict__ ff_w2,
                       float* __restrict__ p0, unsigned short* __restrict__ p0b,
                       unsigned short* __restrict__ e,
                       unsigned short* __restrict__ w1T, unsigned short* __restrict__ w2T,
                       float* __restrict__ zeros) {
  __shared__ float lds[64][65];
  int bx = blockIdx.x, t = threadIdx.x;
  int w = t >> 6, lane = t & 63;

  if (bx < 5120) {  // layernorm roles, wave per row
    int row;
    const float* g;
    const float4* src;
    if (bx < 1024) {           // p = LN(wpe[:4096], g_p)
      row = bx * 4 + w;
      src = (const float4*)(wpe + (size_t)row * 256);
      g = g_p;
    } else {                   // e = LN(wte[tokens], g_e)
      row = (bx - 1024) * 4 + w;
      int tok = tokens[row];
      src = (const float4*)(wte + (size_t)tok * 256);
      g = g_e;
    }
    float4 v = src[lane];
    float mean = wred_sum(v.x + v.y + v.z + v.w) * (1.f / 256.f);
    float4 d = {v.x - mean, v.y - mean, v.z - mean, v.w - mean};
    float var = wred_sum(d.x * d.x + d.y * d.y + d.z * d.z + d.w * d.w) * (1.f / 256.f);
    float r = rsqrtf(var + LN_EPS);
    float4 gv = ((const float4*)g)[lane];
    float4 o = {d.x * r * gv.x, d.y * r * gv.y, d.z * r * gv.z, d.w * r * gv.w};
    ushort4 ob = {f2bf(o.x), f2bf(o.y), f2bf(o.z), f2bf(o.w)};
    if (bx < 1024) {
      ((float4*)(p0 + (size_t)row * 256))[lane] = o;
      ((ushort4*)(p0b + (size_t)row * 256))[lane] = ob;
    } else {
      ((ushort4*)(e + (size_t)row * 256))[lane] = ob;
    }
    return;
  }
  if (bx < 5248) {  // transpose-cast: W1 (256x1024) or W2 (1024x256)
    const float* in; unsigned short* out; int M, N, bxx, byy;
    if (bx < 5184) { int i = bx - 5120; in = ff_w1; out = w1T; M = 256; N = 1024; bxx = i & 3; byy = i >> 2; }
    else           { int i = bx - 5184; in = ff_w2; out = w2T; M = 1024; N = 256; bxx = i & 15; byy = i >> 4; }
    int x = t & 63, y4 = t >> 6;
    int r0 = bxx * 64, c0 = byy * 64;
#pragma unroll
    for (int i = 0; i < 16; ++i) {
      int r = y4 * 16 + i;
      lds[r][x] = in[(size_t)(r0 + r) * N + c0 + x];
    }
    __syncthreads();
#pragma unroll
    for (int i = 0; i < 16; ++i) {
      int a = y4 * 16 + i;
      out[(size_t)(c0 + a) * M + r0 + x] = f2bf(lds[x][a]);
    }
    return;
  }
  // bx == 5248: zero accumulators (ctx 6144 + qall 1536 + xacc 1024 floats, contiguous)
  for (int i = t; i < 6144 + 1536 + 1024; i += 256) zeros[i] = 0.f;
}

// ---------- MFMA GEMM: C(MxN) = A(MxK) @ B, B given as BT(NxK) ----------
template <int TM>
__global__ __launch_bounds__(256) void mfma_gemm(
    const __hip_bfloat16* __restrict__ A, const __hip_bfloat16* __restrict__ BT,
    __hip_bfloat16* __restrict__ Cout, const float* __restrict__ res,
    int M, int N, int K, int mode) {
  constexpr int BM = TM * 32;
  __shared__ __hip_bfloat16 As[BM * 64];
  __shared__ __hip_bfloat16 Bs[64 * 64];
  const int t = threadIdx.x;
  const int lane = t & 63, wave = t >> 6;
  const int wr = wave >> 1, wc = wave & 1;
  const int fr = lane & 15, quad = lane >> 4;
  const int m0 = blockIdx.x * BM, n0 = blockIdx.y * 64;

  f32x4 acc[TM][2];
#pragma unroll
  for (int i = 0; i < TM; ++i)
#pragma unroll
    for (int j = 0; j < 2; ++j) acc[i][j] = (f32x4){0.f, 0.f, 0.f, 0.f};

  for (int k0 = 0; k0 < K; k0 += 64) {
    __syncthreads();
#pragma unroll
    for (int j = 0; j < TM; ++j) {
      int ld = wave * TM + j;
      int slot = ld * 64 + lane;
      int m = slot >> 3, c = slot & 7;
      const __hip_bfloat16* g = A + (size_t)(m0 + m) * K + k0 + ((c ^ (m & 7)) << 3);
      async_cp16(g, As + ld * 512);
    }
#pragma unroll
    for (int j = 0; j < 2; ++j) {
      int ld = wave * 2 + j;
      int slot = ld * 64 + lane;
      int n = slot >> 3, c = slot & 7;
      const __hip_bfloat16* g = BT + (size_t)(n0 + n) * K + k0 + ((c ^ (n & 7)) << 3);
      async_cp16(g, Bs + ld * 512);
    }
    __syncthreads();
#pragma unroll
    for (int h = 0; h < 2; ++h) {
      s8v af[TM], bfv[2];
#pragma unroll
      for (int i = 0; i < TM; ++i) {
        int m = wr * TM * 16 + i * 16 + fr;
        int ch = (h * 4 + quad) ^ (m & 7);
        af[i] = *(const s8v*)(As + m * 64 + ch * 8);
      }
#pragma unroll
      for (int j = 0; j < 2; ++j) {
        int n = wc * 32 + j * 16 + fr;
        int ch = (h * 4 + quad) ^ (n & 7);
        bfv[j] = *(const s8v*)(Bs + n * 64 + ch * 8);
      }
#pragma unroll
      for (int i = 0; i < TM; ++i)
#pragma unroll
        for (int j = 0; j < 2; ++j)
          acc[i][j] = __builtin_amdgcn_mfma_f32_16x16x32_bf16(af[i], bfv[j], acc[i][j], 0, 0, 0);
    }
  }

#pragma unroll
  for (int i = 0; i < TM; ++i) {
#pragma unroll
    for (int j = 0; j < 2; ++j) {
#pragma unroll
      for (int r = 0; r < 4; ++r) {
        int row = m0 + wr * TM * 16 + i * 16 + quad * 4 + r;
        int col = n0 + wc * 32 + j * 16 + fr;
        float v = acc[i][j][r];
        if (mode == 1) v = 0.5f * v * (1.f + erff(v * 0.70710678118654752f));
        if (mode == 2) v += res[(size_t)row * N + col];
        Cout[(size_t)row * N + col] = (__hip_bfloat16)v;
      }
    }
  }
}

// ---------- q[l][t] += sum_{d in chunk} plast[d]*Wq[l][d][t] ----------
__global__ void q_k(const __hip_bfloat16* __restrict__ pB, const float* __restrict__ Wq,
                    float* __restrict__ qall) {
  int c = blockIdx.x, l = blockIdx.y, t = threadIdx.x;
  const __hip_bfloat16* plast = pB + (size_t)4095 * 256;
  const float* W = Wq + (size_t)l * 65536;
  float pa = 0.f;
#pragma unroll
  for (int i = 0; i < 16; ++i) {
    int d = c * 16 + i;
    pa += (float)plast[d] * W[d * 256 + t];  // coalesced over t
  }
  atomicAdd(&qall[l * 256 + t], pa);
}

// ---------- kv[l][r] = Wk[l][r] . q[l]  (wave per row) ----------
__global__ void kv_k(const float* __restrict__ Wk, const float* __restrict__ qall,
                     float* __restrict__ kv) {
  int l = blockIdx.y;
  int w = threadIdx.x >> 6, lane = threadIdx.x & 63;
  int r = blockIdx.x * 4 + w;
  float4 wv = ((const float4*)(Wk + (size_t)l * 65536 + (size_t)r * 256))[lane];
  float4 qv = ((const float4*)(qall + l * 256))[lane];
  float dot = wred_sum(wv.x * qv.x + wv.y * qv.y + wv.z * qv.z + wv.w * qv.w);
  if (lane == 0) kv[l * 256 + r] = dot;
}

// ---------- scores: s[l][t] = p[t] . kv[l] / 16 (wave per row, all 6 layers) ----------
__global__ void scores_k(const __hip_bfloat16* __restrict__ pB, const float* __restrict__ kv,
                         float* __restrict__ sc) {
  int w = threadIdx.x >> 6, lane = threadIdx.x & 63;
  int t = blockIdx.x * 4 + w;
  ushort4 pv = ((const ushort4*)((const unsigned short*)pB + (size_t)t * 256))[lane];
  float4 p = {bf2f(pv.x), bf2f(pv.y), bf2f(pv.z), bf2f(pv.w)};
#pragma unroll
  for (int l = 0; l < 6; ++l) {
    float4 kvv = ((const float4*)(kv + l * 256))[lane];
    float dot = p.x * kvv.x + p.y * kvv.y + p.z * kvv.z + p.w * kvv.w;
    dot = wred_sum(dot);
    if (lane == 0) sc[(size_t)l * 4096 + t] = dot * 0.0625f;
  }
}

// ---------- softmax over 4096 per layer ----------
__global__ void softmax_k(const float* __restrict__ sc, float* __restrict__ w) {
  int l = blockIdx.x, t = threadIdx.x;  // 1024 threads
  float4 v = ((const float4*)(sc + (size_t)l * 4096))[t];
  float m = fmaxf(fmaxf(v.x, v.y), fmaxf(v.z, v.w));
  m = wred_max(m);
  __shared__ float red[16];
  __shared__ float red2[16];
  int lane = t & 63, wv = t >> 6;
  if (lane == 0) red[wv] = m;
  __syncthreads();
  float mm = red[0];
#pragma unroll
  for (int i = 1; i < 16; ++i) mm = fmaxf(mm, red[i]);
  float e0 = expf(v.x - mm), e1 = expf(v.y - mm), e2 = expf(v.z - mm), e3 = expf(v.w - mm);
  float s = wred_sum(e0 + e1 + e2 + e3);
  if (lane == 0) red2[wv] = s;
  __syncthreads();
  float tot = 0.f;
#pragma unroll
  for (int i = 0; i < 16; ++i) tot += red2[i];
  float inv = 1.f / tot;
  float4 o = {e0 * inv, e1 * inv, e2 * inv, e3 * inv};
  ((float4*)(w + (size_t)l * 4096))[t] = o;
}

// ---------- ctx: all 6 layers per block, e read once ----------
__global__ void ctx_k(const unsigned short* __restrict__ e, const float* __restrict__ w,
                      float* __restrict__ ctx) {
  int c = blockIdx.x, b = blockIdx.y, t = threadIdx.x;
  const unsigned short* eb = e + ((size_t)b * 4096 + c * 64) * 256;
  const float* w0 = w + c * 64;
  float a[6] = {0.f, 0.f, 0.f, 0.f, 0.f, 0.f};
#pragma unroll 4
  for (int i = 0; i < 64; ++i) {
    float ev = bf2f(eb[(size_t)i * 256 + t]);
#pragma unroll
    for (int l = 0; l < 6; ++l) a[l] += w0[l * 4096 + i] * ev;
  }
#pragma unroll
  for (int l = 0; l < 6; ++l) atomicAdd(&ctx[(l * 4 + b) * 256 + t], a[l]);
}

// ---------- xacc[b][t] += sum_l sum_{d in chunk} ctx[l][b][d]*Wv[l][d][t] ----------
__global__ void proj_k(const float* __restrict__ ctx, const float* __restrict__ Wv,
                       float* __restrict__ xacc) {
  int c = blockIdx.x, l = blockIdx.y, t = threadIdx.x;
  const float* W = Wv + (size_t)l * 65536;
  float pa[4] = {0.f, 0.f, 0.f, 0.f};
#pragma unroll
  for (int i = 0; i < 16; ++i) {
    int d = c * 16 + i;
    float wv = W[d * 256 + t];  // coalesced
#pragma unroll
    for (int b = 0; b < 4; ++b) pa[b] += ctx[(l * 4 + b) * 256 + d] * wv;  // scalar loads
  }
#pragma unroll
  for (int b = 0; b < 4; ++b) atomicAdd(&xacc[b * 256 + t], pa[b]);
}

// ---------- final: residual + LN ----------
__global__ void final_k(const unsigned short* __restrict__ e, const float* __restrict__ p0,
                        const float* __restrict__ xacc, const float* __restrict__ gout,
                        float* __restrict__ xln) {
  int b = blockIdx.x, t = threadIdx.x;
  float v = xacc[b * 256 + t] + bf2f(e[((size_t)(b * 4096 + 4095)) * 256 + t]) +
            p0[(size_t)4095 * 256 + t];
  __shared__ float s4[4];
  float mean = bsum256(v, s4) * (1.f / 256.f);
  float d = v - mean;
  float var = bsum256(d * d, s4) * (1.f / 256.f);
  xln[b * 256 + t] = d * rsqrtf(var + LN_EPS) * gout[t];
}

// ---------- logits ----------
__global__ void logits_k(const float* __restrict__ wte, const float* __restrict__ ge,
                         const float* __restrict__ xln, float* __restrict__ out) {
  int wv = threadIdx.x >> 6, lane = threadIdx.x & 63;
  int v = blockIdx.x * 4 + wv;
  float4 x = ((const float4*)(wte + (size_t)v * 256))[lane];
  float mean = wred_sum(x.x + x.y + x.z + x.w) * (1.f / 256.f);
  float4 d = {x.x - mean, x.y - mean, x.z - mean, x.w - mean};
  float var = wred_sum(d.x * d.x + d.y * d.y + d.z * d.z + d.w * d.w) * (1.f / 256.f);
  float r = rsqrtf(var + LN_EPS);
  float4 gv = ((const float4*)ge)[lane];
  float4 ln = {d.x * r * gv.x, d.y * r * gv.y, d.z * r * gv.z, d.w * r * gv.w};
#pragma unroll
  for (int b = 0; b < 4; ++b) {
    float4 xv = ((const float4*)(xln + b * 256))[lane];
    float dot = wred_sum(ln.x * xv.x + ln.y * xv.y + ln.z * xv.z + ln.w * xv.w);
    if (lane == 0) out[b * 32000 + v] = dot;
  }
}

// ---------- workspace layout (float units, 16B aligned) ----------
#define O_P0    ((size_t)0)         // f32 4096*256
#define O_E     ((size_t)1048576)   // bf16 16384*256 (2M fl)
#define O_P0B   ((size_t)3145728)   // bf16 4096*256 (512K fl)
#define O_W1T   ((size_t)3670016)   // bf16 1024*256
#define O_W2T   ((size_t)3801088)   // bf16 256*1024
#define O_HB    ((size_t)3932160)   // bf16 4096*1024 (2M fl)
#define O_PB    ((size_t)6029312)   // bf16 4096*256
#define O_CTX   ((size_t)6553600)   // f32 6*4*256 = 6144   (zero block start)
#define O_QALL  ((size_t)6559744)   // f32 6*256  = 1536
#define O_XACC  ((size_t)6561280)   // f32 4*256  = 1024
#define O_KV    ((size_t)6562304)   // f32 6*256
#define O_SC    ((size_t)6563840)   // f32 6*4096
#define O_WSM   ((size_t)6588416)   // f32 6*4096
#define O_XLN   ((size_t)6612992)   // f32 4*256

extern "C" void kernel_launch(void* const* d_in, const int* in_sizes, int n_in,
                              void* d_out, int out_size, void* d_ws, size_t ws_size,
                              hipStream_t stream) {
  const int*   tokens = (const int*)d_in[0];
  const float* wte    = (const float*)d_in[1];
  const float* wpe    = (const float*)d_in[2];
  const float* g_e    = (const float*)d_in[3];
  const float* g_p    = (const float*)d_in[4];
  const float* g_out  = (const float*)d_in[5];
  const float* ff_w1  = (const float*)d_in[6];
  const float* ff_w2  = (const float*)d_in[7];
  const float* Wq     = (const float*)d_in[8];
  const float* Wk     = (const float*)d_in[9];
  const float* Wv     = (const float*)d_in[10];
  float* out = (float*)d_out;
  float* ws = (float*)d_ws;

  float* p0 = ws + O_P0;
  unsigned short* e   = (unsigned short*)(ws + O_E);
  unsigned short* p0b = (unsigned short*)(ws + O_P0B);
  unsigned short* w1T = (unsigned short*)(ws + O_W1T);
  unsigned short* w2T = (unsigned short*)(ws + O_W2T);
  __hip_bfloat16* hB  = (__hip_bfloat16*)(ws + O_HB);
  __hip_bfloat16* pB  = (__hip_bfloat16*)(ws + O_PB);
  float* ctx  = ws + O_CTX;
  float* qall = ws + O_QALL;
  float* xacc = ws + O_XACC;
  float* kv   = ws + O_KV;
  float* sc   = ws + O_SC;
  float* wsm  = ws + O_WSM;
  float* xln  = ws + O_XLN;

  // 1. fused prep (LNs, weight transposes, zero ctx/qall/xacc)
  prep_k<<<5249, 256, 0, stream>>>(wpe, wte, tokens, g_p, g_e, ff_w1, ff_w2,
                                   p0, p0b, e, w1T, w2T, ctx);
  // 2. MLP1: h = gelu(p0 @ ff_w1)  [4096x1024x256]
  mfma_gemm<4><<<dim3(32, 16), 256, 0, stream>>>(
      (const __hip_bfloat16*)p0b, (const __hip_bfloat16*)w1T, hB, nullptr, 4096, 1024, 256, 1);
  // 3. MLP2: p = p0 + h @ ff_w2    [4096x256x1024]
  mfma_gemm<2><<<dim3(64, 4), 256, 0, stream>>>(
      hB, (const __hip_bfloat16*)w2T, pB, p0, 4096, 256, 1024, 2);
  // 4. q = p_last @ Wq (split-D atomics)
  q_k<<<dim3(16, 6), 256, 0, stream>>>(pB, Wq, qall);
  // 5. kv = Wk @ q (wave per row)
  kv_k<<<dim3(64, 6), 256, 0, stream>>>(Wk, qall, kv);
  // 6. scores s[l][t] = p[t].kv[l]/16
  scores_k<<<1024, 256, 0, stream>>>(pB, kv, sc);
  // 7. softmax
  softmax_k<<<6, 1024, 0, stream>>>(sc, wsm);
  // 8. ctx accumulation
  ctx_k<<<dim3(64, 4), 256, 0, stream>>>(e, wsm, ctx);
  // 9. Wv projection (split-D atomics into xacc)
  proj_k<<<dim3(16, 6), 256, 0, stream>>>(ctx, Wv, xacc);
  // 10. residual + final LN
  final_k<<<4, 256, 0, stream>>>(e, p0, xacc, g_out, xln);
  // 11. logits
  logits_k<<<8000, 256, 0, stream>>>(wte, g_e, xln, out);
}